// Round 4
// baseline (764.651 us; speedup 1.0000x reference)
//
#include <hip/hip_runtime.h>

// EHD layer: 3x3 x 8-orientation conv -> argmax+threshold -> 9-bin one-hot
// -> 5x5 box count / 25.
// R7: barrier-free wave-autonomous version (R5 logic, de-risked constructs).
//  - one-hot halo via __shfl_down of prefix sums (intra-wave for 63/64 lanes)
//  - 64-bit shuffle done as two 32-bit __shfl_down (guaranteed overloads)
//  - wave-boundary lanes (t=63,127,191) recompute their 4 halo cols
//    redundantly (same FMA order -> bit-identical)
//  - NO LDS, NO __syncthreads, NO vmcnt(0) drains: stores stream freely
//  - plain mask loads (no readfirstlane), no unroll pragma on main loop

#define NOR 8
#define HH  1024
#define WW  1024
#define H2  1018
#define W2  1018
#define RPB 16
#define NIT (RPB + 4)

__device__ __forceinline__ unsigned long long shfl_down_u64(unsigned long long v)
{
    unsigned int lo = (unsigned int)(v & 0xFFFFFFFFull);
    unsigned int hi = (unsigned int)(v >> 32);
    lo = __shfl_down(lo, 1);
    hi = __shfl_down(hi, 1);
    return ((unsigned long long)hi << 32) | (unsigned long long)lo;
}

__global__ __launch_bounds__(256, 4)
void ehd_rows(const float* __restrict__ x,
              const float* __restrict__ masks,
              float* __restrict__ out)
{
    const int t  = threadIdx.x;
    const int j0 = t * 4;                      // own conv cols j0..j0+3
    const int r0 = blockIdx.x * RPB;
    const int b  = blockIdx.y;
    const float* xb = x + (long)b * HH * WW;

    // masks: thread-uniform scalar loads
    float m[NOR][9];
#pragma unroll
    for (int o = 0; o < NOR; ++o)
#pragma unroll
        for (int k = 0; k < 9; ++k)
            m[o][k] = masks[o * 9 + k];

    // clamped start for the 2-col tail load (t=255 wraps; values unused)
    const int jc = (j0 + 4 > WW - 2) ? (WW - 2) : (j0 + 4);
    // wave-boundary lanes need halo cols j0+4..j0+7 from the NEXT wave ->
    // recompute them locally instead (t=255 has no valid output, excluded)
    const bool bnd = ((t & 63) == 63) && (t != 255);

    // register x-window: rows rr..rr+2; cols j0..j0+5 (all), j0+6..j0+9 (bnd)
    float wr[3][6];
    float wh[3][4];
#pragma unroll
    for (int s = 0; s < 3; ++s) {
        const float4 a  = *reinterpret_cast<const float4*>(xb + (r0 + s) * WW + j0);
        const float2 bb = *reinterpret_cast<const float2*>(xb + (r0 + s) * WW + jc);
        wr[s][0] = a.x; wr[s][1] = a.y; wr[s][2] = a.z; wr[s][3] = a.w;
        wr[s][4] = bb.x; wr[s][5] = bb.y;
        wh[s][0] = 0.f; wh[s][1] = 0.f; wh[s][2] = 0.f; wh[s][3] = 0.f;
        if (bnd) {                              // j0+9 <= 773 for bnd lanes: in range
            const float2 h0 = *reinterpret_cast<const float2*>(xb + (r0 + s) * WW + j0 + 6);
            const float2 h1 = *reinterpret_cast<const float2*>(xb + (r0 + s) * WW + j0 + 8);
            wh[s][0] = h0.x; wh[s][1] = h0.y; wh[s][2] = h1.x; wh[s][3] = h1.y;
        }
    }

    // vertical 5-row ring of horizontal 5-sums, in registers
    unsigned long long hs[5][4];
#pragma unroll
    for (int q = 0; q < 5; ++q)
#pragma unroll
        for (int c = 0; c < 4; ++c) hs[q][c] = 0ull;

    for (int rr = 0; rr < NIT; ++rr) {
        // ---- prefetch x row rr+3 (consumed next iteration)
        int nr = r0 + rr + 3; if (nr > HH - 1) nr = HH - 1;
        const float4 pa = *reinterpret_cast<const float4*>(xb + nr * WW + j0);
        const float2 pb = *reinterpret_cast<const float2*>(xb + nr * WW + jc);
        float ph[4] = {0.f, 0.f, 0.f, 0.f};
        if (bnd) {
            const float2 h0 = *reinterpret_cast<const float2*>(xb + nr * WW + j0 + 6);
            const float2 h1 = *reinterpret_cast<const float2*>(xb + nr * WW + j0 + 8);
            ph[0] = h0.x; ph[1] = h0.y; ph[2] = h1.x; ph[3] = h1.y;
        }

        // ---- conv -> argmax -> threshold -> packed one-hot (own 4 cols)
        unsigned long long ohv[4];
#pragma unroll
        for (int c = 0; c < 4; ++c) {
            float best = 0.0f; int bi = 0;
#pragma unroll
            for (int o = 0; o < NOR; ++o) {
                float acc = wr[0][c] * m[o][0];                 // same order as R2/R3/R4
                acc = fmaf(wr[0][c + 1], m[o][1], acc);
                acc = fmaf(wr[0][c + 2], m[o][2], acc);
                acc = fmaf(wr[1][c    ], m[o][3], acc);
                acc = fmaf(wr[1][c + 1], m[o][4], acc);
                acc = fmaf(wr[1][c + 2], m[o][5], acc);
                acc = fmaf(wr[2][c    ], m[o][6], acc);
                acc = fmaf(wr[2][c + 1], m[o][7], acc);
                acc = fmaf(wr[2][c + 2], m[o][8], acc);
                if (o == 0)          { best = acc; }
                else if (acc > best) { best = acc; bi = o; }
            }
            if (best < 0.9f) bi = NOR;
            ohv[c] = 1ull << (7 * bi);
        }

        // ---- boundary lanes: recompute the 4 halo cols (bit-identical conv)
        unsigned long long hp1 = 0, hp2 = 0, hp3 = 0, hp4 = 0;
        if (bnd) {
            const float xh0[6] = { wr[0][4], wr[0][5], wh[0][0], wh[0][1], wh[0][2], wh[0][3] };
            const float xh1[6] = { wr[1][4], wr[1][5], wh[1][0], wh[1][1], wh[1][2], wh[1][3] };
            const float xh2[6] = { wr[2][4], wr[2][5], wh[2][0], wh[2][1], wh[2][2], wh[2][3] };
            unsigned long long hv[4];
#pragma unroll
            for (int c = 0; c < 4; ++c) {
                float best = 0.0f; int bi = 0;
#pragma unroll
                for (int o = 0; o < NOR; ++o) {
                    float acc = xh0[c] * m[o][0];
                    acc = fmaf(xh0[c + 1], m[o][1], acc);
                    acc = fmaf(xh0[c + 2], m[o][2], acc);
                    acc = fmaf(xh1[c    ], m[o][3], acc);
                    acc = fmaf(xh1[c + 1], m[o][4], acc);
                    acc = fmaf(xh1[c + 2], m[o][5], acc);
                    acc = fmaf(xh2[c    ], m[o][6], acc);
                    acc = fmaf(xh2[c + 1], m[o][7], acc);
                    acc = fmaf(xh2[c + 2], m[o][8], acc);
                    if (o == 0)          { best = acc; }
                    else if (acc > best) { best = acc; bi = o; }
                }
                if (best < 0.9f) bi = NOR;
                hv[c] = 1ull << (7 * bi);
            }
            hp1 = hv[0]; hp2 = hp1 + hv[1]; hp3 = hp2 + hv[2]; hp4 = hp3 + hv[3];
        }

        // ---- neighbor exchange via prefix sums + shfl (no LDS, no barrier)
        const unsigned long long p1 = ohv[0];
        const unsigned long long p2 = p1 + ohv[1];
        const unsigned long long p3 = p2 + ohv[2];
        const unsigned long long p4 = p3 + ohv[3];
        unsigned long long q1 = shfl_down_u64(p1);
        unsigned long long q2 = shfl_down_u64(p2);
        unsigned long long q3 = shfl_down_u64(p3);
        unsigned long long q4 = shfl_down_u64(p4);
        if (bnd) { q1 = hp1; q2 = hp2; q3 = hp3; q4 = hp4; }

        // horizontal 5-sums (7-bit fields: integer adds/subs exact)
        const unsigned long long s0 = p4 + q1;
        const unsigned long long s1 = (p4 - p1) + q2;
        const unsigned long long s2 = (p4 - p2) + q3;
        const unsigned long long s3 = ohv[3] + q4;

        // ---- rotate ring
#pragma unroll
        for (int q = 0; q < 4; ++q)
#pragma unroll
            for (int c = 0; c < 4; ++c) hs[q][c] = hs[q + 1][c];
        hs[4][0] = s0; hs[4][1] = s1; hs[4][2] = s2; hs[4][3] = s3;

        // ---- emit output row ro = r0+rr-4
        if (rr >= 4) {
            const int ro = r0 + rr - 4;
            if (ro < H2 && t < 255) {
                const unsigned long long v0 = hs[0][0] + hs[1][0] + hs[2][0] + hs[3][0] + hs[4][0];
                const unsigned long long v1 = hs[0][1] + hs[1][1] + hs[2][1] + hs[3][1] + hs[4][1];
                const unsigned long long v2 = hs[0][2] + hs[1][2] + hs[2][2] + hs[3][2] + hs[4][2];
                const unsigned long long v3 = hs[0][3] + hs[1][3] + hs[2][3] + hs[3][3] + hs[4][3];
                float* op = out + ((long)b * 9 * H2 + (long)ro) * W2 + j0;
                if (t < 254) {
#pragma unroll
                    for (int k = 0; k < 9; ++k) {
                        const float f0 = (float)((unsigned)(v0 >> (7 * k)) & 0x7Fu) * (1.0f / 25.0f);
                        const float f1 = (float)((unsigned)(v1 >> (7 * k)) & 0x7Fu) * (1.0f / 25.0f);
                        const float f2 = (float)((unsigned)(v2 >> (7 * k)) & 0x7Fu) * (1.0f / 25.0f);
                        const float f3 = (float)((unsigned)(v3 >> (7 * k)) & 0x7Fu) * (1.0f / 25.0f);
                        float2* q2s = reinterpret_cast<float2*>(op + (long)k * H2 * W2);
                        q2s[0] = make_float2(f0, f1);
                        q2s[1] = make_float2(f2, f3);
                    }
                } else {
                    // t=254: cols 1016,1017 valid; 1018,1019 out of range
#pragma unroll
                    for (int k = 0; k < 9; ++k) {
                        const float f0 = (float)((unsigned)(v0 >> (7 * k)) & 0x7Fu) * (1.0f / 25.0f);
                        const float f1 = (float)((unsigned)(v1 >> (7 * k)) & 0x7Fu) * (1.0f / 25.0f);
                        float* q1s = op + (long)k * H2 * W2;
                        q1s[0] = f0;
                        q1s[1] = f1;
                    }
                }
            }
        }

        // ---- rotate register x-window
#pragma unroll
        for (int d = 0; d < 6; ++d) {
            wr[0][d] = wr[1][d];
            wr[1][d] = wr[2][d];
        }
        wr[2][0] = pa.x; wr[2][1] = pa.y; wr[2][2] = pa.z; wr[2][3] = pa.w;
        wr[2][4] = pb.x; wr[2][5] = pb.y;
        if (bnd) {
#pragma unroll
            for (int c = 0; c < 4; ++c) {
                wh[0][c] = wh[1][c];
                wh[1][c] = wh[2][c];
                wh[2][c] = ph[c];
            }
        }
    }
}

extern "C" void kernel_launch(void* const* d_in, const int* in_sizes, int n_in,
                              void* d_out, int out_size, void* d_ws, size_t ws_size,
                              hipStream_t stream)
{
    const float* x     = (const float*)d_in[0];
    const float* masks = (const float*)d_in[1];
    float* out         = (float*)d_out;

    dim3 grid((H2 + RPB - 1) / RPB,   // 64 row stripes
              16);                    // batch
    ehd_rows<<<grid, 256, 0, stream>>>(x, masks, out);
}

// Round 5
// 655.104 us; speedup vs baseline: 1.1672x; 1.1672x over previous
//
#include <hip/hip_runtime.h>

// EHD layer: 3x3 x 8-orientation conv -> argmax+threshold -> 9-bin one-hot
// -> 5x5 box count / 25.
// R8: write-locality geometry. Theory C: kernel is HBM write page-locality
// bound (2.1 TB/s effective vs 6.3 achievable; fill proves the ceiling).
//  - 256 blocks (16 stripes x 16 batch) = 1 block/CU, 512 thr (2 waves/SIMD)
//  - block walks a 64-row stripe sequentially: 9 write streams/block,
//    2304 total (~1 per HBM bank), each advancing 4072 B per iteration
//  - per-iteration barrier KEPT: clusters the 8 waves' stores into one
//    coherent 4 KB burst per plane (R7 showed fragmenting this costs +66us)
//  - thread owns 2 cols: float2 x-loads, float2 stores, no scalar tails
//  - LDS one-hot halo double-buffered, 1 barrier/iter (verified R4 scheme)
//  - conv FMA order + argmax tie rule bit-identical to R4 (absmax 0)

#define NOR 8
#define HH  1024
#define WW  1024
#define H2  1018
#define W2  1018
#define SH  64            // output rows per stripe
#define NIT (SH + 4)      // 68 iterations

__global__ __launch_bounds__(512, 2)
void ehd_rows(const float* __restrict__ x,
              const float* __restrict__ masks,
              float* __restrict__ out)
{
    __shared__ unsigned long long oh[2][1024];   // 16 KB, double-buffered

    const int t  = threadIdx.x;
    const int j0 = t * 2;                        // own conv cols j0, j0+1
    const int r0 = blockIdx.x * SH;
    const int b  = blockIdx.y;
    const float* xb = x + (long)b * HH * WW;

    // masks: thread-uniform scalar loads
    float m[NOR][9];
#pragma unroll
    for (int o = 0; o < NOR; ++o)
#pragma unroll
        for (int k = 0; k < 9; ++k)
            m[o][k] = masks[o * 9 + k];

    const bool cvalid = (j0 <= 1020);    // conv cols j0,j0+1 <= 1021 (t<=510)
    const bool ovalid = (j0 <= W2 - 2);  // out cols j0,j0+1 <= 1017 (t<=508)

    // second float2 covers cols j0+2,j0+3; clamp only engages for t=511
    const int jb = (j0 + 2 > WW - 2) ? (WW - 2) : (j0 + 2);

    // register x-window: rows rr..rr+2, cols j0..j0+3
    float wr[3][4];
#pragma unroll
    for (int s = 0; s < 3; ++s) {
        const float2 A = *reinterpret_cast<const float2*>(xb + (r0 + s) * WW + j0);
        const float2 B = *reinterpret_cast<const float2*>(xb + (r0 + s) * WW + jb);
        wr[s][0] = A.x; wr[s][1] = A.y; wr[s][2] = B.x; wr[s][3] = B.y;
    }

    // vertical 5-row ring of horizontal 5-sums, in registers
    unsigned long long hs[5][2];
#pragma unroll
    for (int q = 0; q < 5; ++q) { hs[q][0] = 0ull; hs[q][1] = 0ull; }

    for (int rr = 0; rr < NIT; ++rr) {
        // ---- prefetch x row rr+3 (consumed next iteration)
        int nr = r0 + rr + 3; if (nr > HH - 1) nr = HH - 1;
        const float2 pa = *reinterpret_cast<const float2*>(xb + nr * WW + j0);
        const float2 pb = *reinterpret_cast<const float2*>(xb + nr * WW + jb);

        unsigned long long* ohb = oh[rr & 1];

        // ---- conv -> argmax -> threshold -> packed one-hot (2 cols)
        if (cvalid) {
            unsigned long long ov[2];
#pragma unroll
            for (int c = 0; c < 2; ++c) {
                float best = 0.0f; int bi = 0;
#pragma unroll
                for (int o = 0; o < NOR; ++o) {
                    float acc = wr[0][c] * m[o][0];             // same order as R2/R3/R4
                    acc = fmaf(wr[0][c + 1], m[o][1], acc);
                    acc = fmaf(wr[0][c + 2], m[o][2], acc);
                    acc = fmaf(wr[1][c    ], m[o][3], acc);
                    acc = fmaf(wr[1][c + 1], m[o][4], acc);
                    acc = fmaf(wr[1][c + 2], m[o][5], acc);
                    acc = fmaf(wr[2][c    ], m[o][6], acc);
                    acc = fmaf(wr[2][c + 1], m[o][7], acc);
                    acc = fmaf(wr[2][c + 2], m[o][8], acc);
                    if (o == 0)          { best = acc; }
                    else if (acc > best) { best = acc; bi = o; }
                }
                if (best < 0.9f) bi = NOR;
                ov[c] = 1ull << (7 * bi);
            }
            ulonglong2 wv; wv.x = ov[0]; wv.y = ov[1];
            *reinterpret_cast<ulonglong2*>(&ohb[j0]) = wv;      // 16B aligned
        }
        __syncthreads();

        // ---- horizontal 5-sums + vertical ring + emit
        if (ovalid) {
            const ulonglong2 A  = *reinterpret_cast<const ulonglong2*>(&ohb[j0]);
            const ulonglong2 Bv = *reinterpret_cast<const ulonglong2*>(&ohb[j0 + 2]);
            const ulonglong2 Cv = *reinterpret_cast<const ulonglong2*>(&ohb[j0 + 4]);
            const unsigned long long s0 = A.x + A.y + Bv.x + Bv.y + Cv.x;
            const unsigned long long s1 = s0 - A.x + Cv.y;      // 7-bit fields: exact

#pragma unroll
            for (int q = 0; q < 4; ++q) { hs[q][0] = hs[q + 1][0]; hs[q][1] = hs[q + 1][1]; }
            hs[4][0] = s0; hs[4][1] = s1;

            if (rr >= 4) {
                const int ro = r0 + rr - 4;
                if (ro < H2) {
                    const unsigned long long v0 = hs[0][0] + hs[1][0] + hs[2][0] + hs[3][0] + hs[4][0];
                    const unsigned long long v1 = hs[0][1] + hs[1][1] + hs[2][1] + hs[3][1] + hs[4][1];
                    float* op = out + (long)b * 9 * H2 * W2 + (long)ro * W2 + j0;
#pragma unroll
                    for (int k = 0; k < 9; ++k) {
                        const float f0 = (float)((unsigned)(v0 >> (7 * k)) & 0x7Fu) * (1.0f / 25.0f);
                        const float f1 = (float)((unsigned)(v1 >> (7 * k)) & 0x7Fu) * (1.0f / 25.0f);
                        *reinterpret_cast<float2*>(op + (long)k * H2 * W2) = make_float2(f0, f1);
                    }
                }
            }
        }
        // next iteration writes the OTHER oh buffer; this iteration's barrier
        // orders all reads of ohb before any rewrite two iterations later.

        // ---- rotate register x-window
#pragma unroll
        for (int d = 0; d < 4; ++d) { wr[0][d] = wr[1][d]; wr[1][d] = wr[2][d]; }
        wr[2][0] = pa.x; wr[2][1] = pa.y; wr[2][2] = pb.x; wr[2][3] = pb.y;
    }
}

extern "C" void kernel_launch(void* const* d_in, const int* in_sizes, int n_in,
                              void* d_out, int out_size, void* d_ws, size_t ws_size,
                              hipStream_t stream)
{
    const float* x     = (const float*)d_in[0];
    const float* masks = (const float*)d_in[1];
    float* out         = (float*)d_out;

    dim3 grid(16,    // 16 row stripes of 64 rows (16*64 = 1024 >= 1018)
              16);   // batch
    ehd_rows<<<grid, 512, 0, stream>>>(x, masks, out);
}